// Round 5
// baseline (1174.245 us; speedup 1.0000x reference)
//
#include <hip/hip_runtime.h>

// ---------------------------------------------------------------------------
// MultiScaleRetention forward, MI355X/gfx950.  B=1,T=4096,E=1024,VD=2048,H=8.
// R5: attention = (head x 32q-rows) blocks, 8 waves = hd-half x s-quarter,
// LDS-atomic combine (no barriers in loop, no global atomics); rotary fused
// into qkvg GEMM epilogue (K-scale folded into Wk); plain-store out-GEMM.
// ---------------------------------------------------------------------------

typedef __attribute__((ext_vector_type(8)))  short  short8;
typedef __attribute__((ext_vector_type(16))) float  floatx16;

__device__ inline unsigned short f2bf(float f){
  unsigned int u = __builtin_bit_cast(unsigned int, f);
  unsigned int r = (u + 0x7fffu + ((u >> 16) & 1u)) >> 16;   // RNE
  return (unsigned short)r;
}
__device__ inline float bf2f(unsigned short u){
  unsigned int x = ((unsigned int)u) << 16;
  return __builtin_bit_cast(float, x);
}
__device__ inline void async_cp16(const void* g, const void* l){
  __builtin_amdgcn_global_load_lds((const __attribute__((address_space(1))) void*)g,
                                   (__attribute__((address_space(3))) void*)l, 16, 0, 0);
}

// ---------------- x -> bf16 -------------------------------------------------
struct us4 { unsigned short a,b,c,d; };
__global__ void k_cvt_x(const float* __restrict__ x, unsigned short* __restrict__ xb, int n4){
  int i = blockIdx.x*blockDim.x + threadIdx.x;
  if (i >= n4) return;
  float4 v = ((const float4*)x)[i];
  us4 o = { f2bf(v.x), f2bf(v.y), f2bf(v.z), f2bf(v.w) };
  ((us4*)xb)[i] = o;
}

// ---------------- fused weight transposes (fp32 RxC -> bf16 CxR, x scale) ---
struct WPrep  { const float* src; unsigned short* dst; int R; int C; int ntile; float scale; };
struct WPrepAll { WPrep w[5]; };
__global__ __launch_bounds__(256) void k_prep_w(WPrepAll a){
  __shared__ float tile[64][65];
  int b = blockIdx.x, i = 0;
  while (b >= a.w[i].ntile){ b -= a.w[i].ntile; ++i; }
  const float* src = a.w[i].src; unsigned short* dst = a.w[i].dst;
  int R = a.w[i].R, C = a.w[i].C;
  float sc = a.w[i].scale;
  int tpr = C >> 6;
  int c0 = (b % tpr)*64, r0 = (b / tpr)*64;
  #pragma unroll
  for (int j=0;j<16;++j){
    int idx = j*256 + threadIdx.x; int r = idx>>6, c = idx&63;
    tile[r][c] = src[(size_t)(r0+r)*C + c0 + c];
  }
  __syncthreads();
  #pragma unroll
  for (int j=0;j<16;++j){
    int idx = j*256 + threadIdx.x; int r = idx>>6, c = idx&63;
    dst[(size_t)(c0+r)*R + r0 + c] = f2bf(tile[c][r] * sc);
  }
}

// ---------------- bf16 (R,C) -> bf16 (C,R) transpose ------------------------
__global__ __launch_bounds__(256) void k_transpose_b2b(const unsigned short* __restrict__ src,
    unsigned short* __restrict__ dst, int R, int C){
  __shared__ unsigned short tile[64][72];
  int c0 = blockIdx.x*64, r0 = blockIdx.y*64;
  #pragma unroll
  for (int i=0;i<16;++i){
    int idx = i*256 + threadIdx.x; int r = idx>>6, c = idx&63;
    tile[r][c] = src[(size_t)(r0+r)*C + c0 + c];
  }
  __syncthreads();
  #pragma unroll
  for (int i=0;i<16;++i){
    int idx = i*256 + threadIdx.x; int r = idx>>6, c = idx&63;
    dst[(size_t)(c0+r)*R + r0 + c] = tile[c][r];
  }
}

// ---------------- bf16 GEMM: C(M,N) = A(M,K) * BT(N,K)^T --------------------
// MODE 0: qkvg fanout epilogue with FUSED ROTARY for q/k columns (partner
// element via shfl_xor(1); K pre-scaled in Wk transpose). MODE 1: plain fp32.
template<int MODE>
__global__ __launch_bounds__(256) void k_gemm_bt(
    const unsigned short* __restrict__ A, const unsigned short* __restrict__ BT,
    int M, int N, int K,
    float* __restrict__ out_f32, unsigned short* __restrict__ out_v,
    unsigned short* __restrict__ out_g,
    const float* __restrict__ sinp, const float* __restrict__ cosp,
    unsigned short* __restrict__ out_q, unsigned short* __restrict__ out_k)
{
  __shared__ __align__(16) short As[128*64];
  __shared__ __align__(16) short Bs[128*64];
  int bn = blockIdx.x*128, bm = blockIdx.y*128;
  int tid = threadIdx.x;
  int w = tid>>6, l = tid&63;
  int wr = w>>1, wc = w&1;
  int lrow = l&31, lhi = l>>5;
  floatx16 acc[2][2];
  #pragma unroll
  for (int a=0;a<2;++a)
    #pragma unroll
    for (int b=0;b<2;++b)
      #pragma unroll
      for (int j=0;j<16;++j) acc[a][b][j]=0.f;

  for (int k0=0; k0<K; k0+=64){
    __syncthreads();
    #pragma unroll
    for (int i=0;i<4;++i){
      int idx = i*256 + tid; int r = idx>>3, c = idx&7;
      int cs = c ^ (r&7);
      async_cp16((const char*)A  + ((size_t)(bm+r)*K + k0 + cs*8)*2, &As[idx*8]);
      async_cp16((const char*)BT + ((size_t)(bn+r)*K + k0 + cs*8)*2, &Bs[idx*8]);
    }
    __syncthreads();
    #pragma unroll
    for (int kc=0;kc<4;++kc){
      short8 af[2], bf[2];
      #pragma unroll
      for (int tm=0;tm<2;++tm){
        int row = wr*64 + tm*32 + lrow;
        int pos = (2*kc + lhi) ^ (row&7);
        af[tm] = *(const short8*)&As[row*64 + pos*8];
      }
      #pragma unroll
      for (int tn=0;tn<2;++tn){
        int row = wc*64 + tn*32 + lrow;
        int pos = (2*kc + lhi) ^ (row&7);
        bf[tn] = *(const short8*)&Bs[row*64 + pos*8];
      }
      #pragma unroll
      for (int tm=0;tm<2;++tm)
        #pragma unroll
        for (int tn=0;tn<2;++tn)
          acc[tm][tn] = __builtin_amdgcn_mfma_f32_32x32x16_bf16(af[tm], bf[tn], acc[tm][tn], 0,0,0);
    }
  }
  #pragma unroll
  for (int tm=0;tm<2;++tm)
    #pragma unroll
    for (int tn=0;tn<2;++tn){
      int colq = bn + wc*64 + tn*32;          // quadrant column base (uniform)
      #pragma unroll
      for (int r=0;r<16;++r){
        int row = bm + wr*64 + tm*32 + (r&3) + 8*(r>>2) + 4*lhi;
        int col = colq + lrow;
        float v = acc[tm][tn][r];
        if (MODE==0){
          if (colq < 2048){
            // fused rotary: partner element (col^1) lives in lane l^1
            float p = __shfl_xor(v, 1);
            int d = col & 127;
            float sn = sinp[row*128 + d], cs = cosp[row*128 + d];
            float rv = v*cs + ((col&1) ? p*sn : -p*sn);
            if (colq < 1024) out_q[(size_t)row*1024 + col]        = f2bf(rv);
            else             out_k[(size_t)row*1024 + (col-1024)] = f2bf(rv);
          }
          else if (colq < 4096) out_v[(size_t)row*2048 + (col-2048)] = f2bf(v);
          else                  out_g[(size_t)row*2048 + (col-4096)] = f2bf(v);
        } else {
          out_f32[(size_t)row*N + col] = v;
        }
      }
    }
}

// ---------------- retention attention (s-split + LDS combine) ---------------
// Grid: 1024 blocks = head(8) x qunit(128 of 32 rows, longest-first).
// 512 thr = 8 waves = (s-quarter sq 0..3) x (hd-half hh 0..1).
// Wave: 32 q-rows x 128 hd over <=32 s-tiles; K/V frags direct from
// L2-resident global; K prefetch; dual QK chains; wave-private P roundtrip;
// incremental decay tf. Partial O/den combined via LDS fp32 atomics.
__global__ __launch_bounds__(512) void k_attn(
    const unsigned short* __restrict__ qr, const unsigned short* __restrict__ kr,
    const unsigned short* __restrict__ vT, unsigned short* __restrict__ o_out)
{
  __shared__ float oL[2][32][128];
  __shared__ float denL[32];
  __shared__ __align__(16) short Ps[8][32*40];

  int b = blockIdx.x;
  int head = b & 7;
  int qu   = 127 - (b >> 3);                   // longest first
  int tbase = qu*32;
  int tid = threadIdx.x;
  int w = tid>>6, l = tid&63;
  int hh = w & 1, sq = w >> 1;
  int lrow = l&31, lhi = l>>5;

  // zero the combine buffers
  {
    float4 z = {0.f,0.f,0.f,0.f};
    float4* p = (float4*)&oL[0][0][0];         // 8192 floats = 2048 float4
    #pragma unroll
    for (int i=0;i<4;++i) p[tid + i*512] = z;
    if (tid < 32) denL[tid] = 0.f;
  }
  __syncthreads();

  float gamma = 1.f - exp2f(-5.f - (float)head);
  float L = log2f(gamma);                      // negative
  int dmax = (int)(40.0f/(-L));
  int lo = tbase - dmax; if (lo < 0) lo = 0; lo &= ~31;
  int n_t = ((tbase - lo) >> 5) + 1;           // total s-tiles
  int per = (n_t + 3) >> 2;
  int i0 = sq*per;
  int i1 = i0 + per; if (i1 > n_t) i1 = n_t;
  bool work = i0 < i1;

  float den[16];
  #pragma unroll
  for (int r=0;r<16;++r) den[r]=0.f;
  floatx16 o[4];
  #pragma unroll
  for (int i=0;i<4;++i)
    #pragma unroll
    for (int j=0;j<16;++j) o[i][j]=0.f;

  if (work){
    int s_lo = lo + (i0<<5);
    int s_hi = lo + ((i1-1)<<5);

    short8 qf[8];
    const unsigned short* qbase = qr + (size_t)(tbase+lrow)*1024 + head*128 + lhi*8;
    #pragma unroll
    for (int kc=0;kc<8;++kc) qf[kc] = *(const short8*)(qbase + kc*16);

    float rc[16];                              // gamma^(row-lrow)
    #pragma unroll
    for (int r=0;r<16;++r){
      int row = (r&3)+8*(r>>2)+4*lhi;
      rc[r] = exp2f(L*(float)(row - lrow));
    }
    float tf  = exp2f(L*(float)(tbase - s_lo));
    float gup = exp2f(-32.f*L);                // tf growth per +32 s

    short* myP = &Ps[w][0];
    const unsigned short* kb = kr + head*128 + lhi*8;
    const unsigned short* vb = vT + (size_t)(head*256 + hh*128)*4096 + lhi*8;

    short8 kf[8];
    {
      const unsigned short* kp = kb + (size_t)(s_lo+lrow)*1024;
      #pragma unroll
      for (int kc=0;kc<8;++kc) kf[kc] = *(const short8*)(kp + kc*16);
    }

    for (int s0 = s_lo; s0 <= s_hi; s0 += 32){
      // V fragments (independent -> issue early)
      short8 vv[4][2];
      const unsigned short* vp = vb + s0;
      #pragma unroll
      for (int nt=0;nt<4;++nt){
        const unsigned short* vr = vp + (size_t)(nt*32+lrow)*4096;
        #pragma unroll
        for (int kc=0;kc<2;++kc) vv[nt][kc] = *(const short8*)(vr + kc*16);
      }
      // QK^T, two independent 4-deep chains
      floatx16 sA, sB;
      #pragma unroll
      for (int j=0;j<16;++j){ sA[j]=0.f; sB[j]=0.f; }
      #pragma unroll
      for (int kc=0;kc<4;++kc)
        sA = __builtin_amdgcn_mfma_f32_32x32x16_bf16(qf[kc],   kf[kc],   sA, 0,0,0);
      #pragma unroll
      for (int kc=0;kc<4;++kc)
        sB = __builtin_amdgcn_mfma_f32_32x32x16_bf16(qf[kc+4], kf[kc+4], sB, 0,0,0);
      // prefetch next K tile
      int sn = (s0 + 32 <= s_hi) ? s0 + 32 : s0;
      short8 kn[8];
      {
        const unsigned short* kp = kb + (size_t)(sn+lrow)*1024;
        #pragma unroll
        for (int kc=0;kc<8;++kc) kn[kc] = *(const short8*)(kp + kc*16);
      }
      // decay + den + P (wave-private LDS, no barrier)
      bool diag = (s0 + 31 > tbase);
      #pragma unroll
      for (int r=0;r<16;++r){
        int row = (r&3)+8*(r>>2)+4*lhi;
        float val = (sA[r]+sB[r])*(tf*rc[r]);
        if (diag){ if (tbase+row < s0+lrow) val = 0.f; }
        den[r] += fabsf(val);
        myP[row*40 + lrow] = (short)f2bf(val);
      }
      short8 pa[2];
      #pragma unroll
      for (int kc=0;kc<2;++kc)
        pa[kc] = *(const short8*)&myP[lrow*40 + kc*16 + lhi*8];
      #pragma unroll
      for (int nt=0;nt<4;++nt)
        #pragma unroll
        for (int kc=0;kc<2;++kc)
          o[nt] = __builtin_amdgcn_mfma_f32_32x32x16_bf16(pa[kc], vv[nt][kc], o[nt], 0,0,0);
      #pragma unroll
      for (int kc=0;kc<8;++kc) kf[kc] = kn[kc];
      tf *= gup;
    }

    // combine: O into LDS via fp32 atomics
    #pragma unroll
    for (int nt=0;nt<4;++nt)
      #pragma unroll
      for (int r=0;r<16;++r){
        int row = (r&3)+8*(r>>2)+4*lhi;
        atomicAdd(&oL[hh][row][nt*32+lrow], o[nt][r]);
      }
    // den: reduce across the 32 cols, then 1 lane per half adds 16 rows
    if (hh == 0){
      #pragma unroll
      for (int r=0;r<16;++r){
        float d = den[r];
        #pragma unroll
        for (int off=1; off<32; off<<=1) d += __shfl_xor(d, off, 64);
        den[r] = d;
      }
      if (lrow == 0){
        #pragma unroll
        for (int r=0;r<16;++r){
          int row = (r&3)+8*(r>>2)+4*lhi;
          atomicAdd(&denL[row], den[r]);
        }
      }
    }
  }
  __syncthreads();

  // epilogue: normalize + bf16 store.  512 thr = (hh, row, 8 hd-groups of 16)
  {
    int ehh  = tid >> 8;
    int erow = (tid >> 3) & 31;
    int ehd  = (tid & 7) * 16;
    float dn = denL[erow];
    float inv = 1.0f/fminf(fmaxf(dn, 1.0f), 50000.0f);
    const float* src = &oL[ehh][erow][ehd];
    short8 o0, o1;
    #pragma unroll
    for (int j=0;j<8;++j) o0[j] = (short)f2bf(src[j]   * inv);
    #pragma unroll
    for (int j=0;j<8;++j) o1[j] = (short)f2bf(src[8+j] * inv);
    unsigned short* dst = o_out + (size_t)(tbase+erow)*2048 + head*256 + ehh*128 + ehd;
    *(short8*)dst = o0;
    *(short8*)(dst+8) = o1;
  }
}

// ---------------- group RMS + SiLU gate -------------------------------------
__global__ __launch_bounds__(256) void k_rmsgate(const unsigned short* __restrict__ o_bf16,
    const unsigned short* __restrict__ g_bf16, unsigned short* __restrict__ gated)
{
  int t = blockIdx.x;
  int tid = threadIdx.x;
  size_t base = (size_t)t*2048 + tid*8;     // 32 threads = one head group (256)
  short8 ov = *(const short8*)(o_bf16 + base);
  short8 gv = *(const short8*)(g_bf16 + base);
  float of[8], gf[8]; float ss = 0.f;
  #pragma unroll
  for (int j=0;j<8;++j){
    of[j]=bf2f((unsigned short)ov[j]);
    gf[j]=bf2f((unsigned short)gv[j]);
    ss += of[j]*of[j];
  }
  #pragma unroll
  for (int off=1; off<32; off<<=1) ss += __shfl_xor(ss, off, 64);
  float rms = rsqrtf(ss*(1.0f/256.0f) + 1e-6f);
  short8 outv;
  #pragma unroll
  for (int j=0;j<8;++j){
    float g = gf[j];
    float si = g / (1.0f + expf(-g));
    outv[j] = (short)f2bf(si * of[j] * rms);
  }
  *(short8*)(gated + base) = outv;
}

// ---------------------------------------------------------------------------
extern "C" void kernel_launch(void* const* d_in, const int* in_sizes, int n_in,
                              void* d_out, int out_size, void* d_ws, size_t ws_size,
                              hipStream_t stream)
{
  const float* x    = (const float*)d_in[0];
  const float* sinp = (const float*)d_in[1];
  const float* cosp = (const float*)d_in[2];
  // d_in[3] = inner_mask: intentionally unused (computed analytically)
  const float* Wq = (const float*)d_in[4];
  const float* Wk = (const float*)d_in[5];
  const float* Wv = (const float*)d_in[6];
  const float* Wg = (const float*)d_in[7];
  const float* Wo = (const float*)d_in[8];

  char* ws = (char*)d_ws;
  size_t off = 0;
  auto alloc = [&](size_t bytes)->char*{ char* p = ws + off; off += (bytes + 255) & ~(size_t)255; return p; };
  unsigned short* x_bf   = (unsigned short*)alloc((size_t)4096*1024*2);
  unsigned short* WallT  = (unsigned short*)alloc((size_t)6144*1024*2);
  unsigned short* qrp    = (unsigned short*)alloc((size_t)4096*1024*2);
  unsigned short* krp    = (unsigned short*)alloc((size_t)4096*1024*2);
  unsigned short* v_bf   = (unsigned short*)alloc((size_t)4096*2048*2);
  unsigned short* g_bf   = (unsigned short*)alloc((size_t)4096*2048*2);
  unsigned short* vT     = (unsigned short*)alloc((size_t)2048*4096*2);
  unsigned short* WoT    = (unsigned short*)alloc((size_t)1024*2048*2);
  unsigned short* o_bf   = (unsigned short*)alloc((size_t)4096*2048*2);
  unsigned short* gated  = (unsigned short*)alloc((size_t)4096*2048*2);

  // prep (Wk pre-scaled by KD^-0.5; rotary is linear so this is exact)
  k_cvt_x<<<4096, 256, 0, stream>>>(x, x_bf, 4096*1024/4);
  WPrepAll pa;
  pa.w[0] = { Wq, WallT,                     1024, 1024, 256, 1.0f };
  pa.w[1] = { Wk, WallT + 1024*1024,         1024, 1024, 256, 0.08838834764831845f };
  pa.w[2] = { Wv, WallT + 2048*1024,         1024, 2048, 512, 1.0f };
  pa.w[3] = { Wg, WallT + (size_t)4096*1024, 1024, 2048, 512, 1.0f };
  pa.w[4] = { Wo, WoT,                       2048, 1024, 512, 1.0f };
  k_prep_w<<<2048, 256, 0, stream>>>(pa);

  // qkvg = x @ [Wq|Wk|Wv|Wg] with fused rotary -> qr/kr bf16 direct
  k_gemm_bt<0><<<dim3(48,32), 256, 0, stream>>>(x_bf, WallT, 4096, 6144, 1024,
      nullptr, v_bf, g_bf, sinp, cosp, qrp, krp);

  // V^T per head: (t, 2048) -> (2048, t)
  k_transpose_b2b<<<dim3(32,64), 256, 0, stream>>>(v_bf, vT, 4096, 2048);

  // retention attention -> o_bf (t, h*256+hd), den-normalized
  k_attn<<<1024, 512, 0, stream>>>(qrp, krp, vT, o_bf);

  // RMS(group=256) + silu(g) gate -> gated bf16
  k_rmsgate<<<4096, 256, 0, stream>>>(o_bf, g_bf, gated);

  // out = gated @ Wo -> fp32 d_out (plain stores, full overwrite)
  k_gemm_bt<1><<<dim3(8,32), 256, 0, stream>>>(gated, WoT, 4096, 1024, 2048,
      (float*)d_out, nullptr, nullptr, nullptr, nullptr, nullptr, nullptr);

  (void)in_sizes; (void)n_in; (void)out_size; (void)ws_size;
}